// Round 2
// baseline (316.170 us; speedup 1.0000x reference)
//
#include <hip/hip_runtime.h>

#define D_MODEL 1024
#define SEQ     2048
#define BATCH   2
#define NHEAD   16
#define HDIM    64

typedef __attribute__((ext_vector_type(4))) float  f32x4;
typedef __attribute__((ext_vector_type(8))) __bf16 bf16x8;
typedef __attribute__((ext_vector_type(4))) __bf16 bf16x4;

__device__ __forceinline__ void gld_lds16(const void* g, void* l) {
  __builtin_amdgcn_global_load_lds(
      (const __attribute__((address_space(1))) void*)g,
      (__attribute__((address_space(3))) void*)l, 16, 0, 0);
}

// ---------------- convert x (fp32 -> bf16), vectorized ----------------
__global__ void k_convert(const float* __restrict__ in, __bf16* __restrict__ out) {
  int i = blockIdx.x * blockDim.x + threadIdx.x;   // one float4 per thread
  float4 v = ((const float4*)in)[i];
  bf16x4 o;
  o[0] = (__bf16)v.x; o[1] = (__bf16)v.y; o[2] = (__bf16)v.z; o[3] = (__bf16)v.w;
  ((bf16x4*)out)[i] = o;
}

// ------------- transpose + convert weights: W[k][n] -> Wt[n][k] bf16 -------------
__global__ void k_transw(const float* __restrict__ Wq, const float* __restrict__ Wk,
                         const float* __restrict__ Wv, const float* __restrict__ Wo,
                         __bf16* __restrict__ Wqkvt, __bf16* __restrict__ Wot) {
  __shared__ __bf16 T[64][72];                      // 72*2B=144B rows (16B-aligned chunks)
  const int z = blockIdx.z;
  const float* src = (z==0)?Wq:(z==1)?Wk:(z==2)?Wv:Wo;
  __bf16* dst = (z<3) ? (Wqkvt + (size_t)z*D_MODEL*D_MODEL) : Wot;
  const int k0 = blockIdx.x*64, n0 = blockIdx.y*64;
  const int t = threadIdx.x;
  const int kl = t>>4, nl4 = (t&15)*4;
  // FIX(R1): load ALL 64 k-rows (was only 16 -> 3/4 of T uninitialized)
  #pragma unroll
  for (int part = 0; part < 4; ++part) {
    const int k = part*16 + kl;
    float4 v = *(const float4*)(src + (size_t)(k0+k)*D_MODEL + n0 + nl4);
    T[nl4+0][k] = (__bf16)v.x;
    T[nl4+1][k] = (__bf16)v.y;
    T[nl4+2][k] = (__bf16)v.z;
    T[nl4+3][k] = (__bf16)v.w;
  }
  __syncthreads();
  const int nl = t>>3, kc = (t&7)*8;
  #pragma unroll
  for (int part = 0; part < 2; ++part) {
    int n = part*32 + nl;
    bf16x8 o = *(const bf16x8*)&T[n][kc];
    *(bf16x8*)(dst + (size_t)(n0+n)*D_MODEL + k0 + kc) = o;
  }
}

// ------------- bf16 MFMA GEMM, 128x128 tile, BK=32, Bt is [N][K] (m97 structure) -------------
// OUTF32=0: bf16 store. OUTF32=1: fp32 store + bias.
template<int OUTF32>
__global__ __launch_bounds__(256)
void k_gemm_bt(const __bf16* __restrict__ A, const __bf16* __restrict__ Bt,
               void* __restrict__ Cv, const float* __restrict__ bias,
               const int K, const int N) {
  __shared__ __bf16 As[128*32];   // 8 KiB, linear [row][k], 64B rows
  __shared__ __bf16 Bs[128*32];
  const int t = threadIdx.x;
  const int w = t>>6, l = t&63;
  const int lr = l&15, g = l>>4;
  const int m0 = blockIdx.y*128, n0 = blockIdx.x*128;
  const int wr = (w>>1)*64, wc = (w&1)*64;
  f32x4 acc[4][4] = {};

  const int srow = w*16 + (l>>2);          // staging row (+64 on 2nd issue)
  const int sc8  = (l&3)*8;                // staging k-chunk (8 bf16)
  const __bf16* Ag = A  + (size_t)(m0 + srow)*K + sc8;
  const __bf16* Bg = Bt + (size_t)(n0 + srow)*K + sc8;
  char* Al = (char*)As + w*1024;           // HW adds lane*16
  char* Bl = (char*)Bs + w*1024;

  for (int k0 = 0; k0 < K; k0 += 32) {
    __syncthreads();
    gld_lds16(Ag + k0,                 Al);
    gld_lds16(Ag + (size_t)64*K + k0,  Al + 4096);
    gld_lds16(Bg + k0,                 Bl);
    gld_lds16(Bg + (size_t)64*K + k0,  Bl + 4096);
    __syncthreads();
    bf16x8 af[4], bf[4];
    #pragma unroll
    for (int mi=0;mi<4;++mi)
      af[mi] = *(const bf16x8*)((const char*)As + (wr + mi*16 + lr)*64 + (g<<4));
    #pragma unroll
    for (int ni=0;ni<4;++ni)
      bf[ni] = *(const bf16x8*)((const char*)Bs + (wc + ni*16 + lr)*64 + (g<<4));
    #pragma unroll
    for (int mi=0;mi<4;++mi)
      #pragma unroll
      for (int ni=0;ni<4;++ni)
        acc[mi][ni] = __builtin_amdgcn_mfma_f32_16x16x32_bf16(af[mi], bf[ni], acc[mi][ni], 0, 0, 0);
  }

  if (OUTF32) {
    float* C = (float*)Cv;
    #pragma unroll
    for (int ni=0;ni<4;++ni) {
      const int col = n0 + wc + ni*16 + lr;
      const float bv = bias[col];
      #pragma unroll
      for (int mi=0;mi<4;++mi)
        #pragma unroll
        for (int r=0;r<4;++r) {
          const int row = m0 + wr + mi*16 + g*4 + r;
          C[(size_t)row*N + col] = acc[mi][ni][r] + bv;
        }
    }
  } else {
    __bf16* C = (__bf16*)Cv;
    #pragma unroll
    for (int ni=0;ni<4;++ni) {
      const int col = n0 + wc + ni*16 + lr;
      #pragma unroll
      for (int mi=0;mi<4;++mi)
        #pragma unroll
        for (int r=0;r<4;++r) {
          const int row = m0 + wr + mi*16 + g*4 + r;
          C[(size_t)row*N + col] = (__bf16)acc[mi][ni][r];
        }
    }
  }
}

// ------------- causal flash attention -------------
// QKV: [4096][3072] bf16 (cols 0:1024 Q, 1024:2048 K, 2048:3072 V, per-head 64)
// AO:  [4096][1024] bf16
__global__ __launch_bounds__(256)
void k_attn(const __bf16* __restrict__ QKV, __bf16* __restrict__ AO) {
  __shared__ __bf16 Ks[32*64];     // [key][dh], 128B rows, chunk ^= (key&7)
  __shared__ __bf16 Vt[64*32];     // [dh][key], 64B rows, chunk ^= sw(dh)
  __shared__ __bf16 Ps[4][16*32];  // per-wave P scratch, chunk ^= (row>>2)&3
  const int t = threadIdx.x;
  const int w = t>>6, l = t&63;
  const int lr = l&15, g = l>>4;
  const int qb = blockIdx.x, bh = blockIdx.y;
  const int b = bh>>4, h = bh&15;
  const size_t rb = (size_t)b*SEQ;
  const int q0 = qb*64 + w*16;

  // Q fragments held in registers for the whole block
  bf16x8 qf[2];
  #pragma unroll
  for (int kc=0;kc<2;++kc)
    qf[kc] = *(const bf16x8*)(QKV + (rb + q0 + lr)*3072 + h*64 + kc*32 + g*8);

  f32x4 oacc[4] = {};
  float mrow[4], lrow[4];
  #pragma unroll
  for (int r=0;r<4;++r){ mrow[r] = -1e30f; lrow[r] = 0.f; }

  const int skey = t>>3, sc = t&7;           // staging: key 0..31, chunk 0..7
  const __bf16* Kg = QKV + (rb + skey)*3072 + 1024 + h*64 + sc*8;
  const __bf16* Vg = Kg + 1024;
  char* KsW = (char*)Ks + skey*128 + ((sc ^ (skey&7))<<4);

  const int ktmax = 2*(qb+1);                // causal skip
  for (int kt = 0; kt < ktmax; ++kt) {
    __syncthreads();
    uint4 kv = *(const uint4*)(Kg + (size_t)kt*32*3072);
    uint4 vv = *(const uint4*)(Vg + (size_t)kt*32*3072);
    *(uint4*)KsW = kv;
    const ushort* vs = (const ushort*)&vv;
    #pragma unroll
    for (int j=0;j<8;++j) {                  // V transposed into LDS
      int dh = sc*8 + j;
      int sw = ((dh>>1) ^ (dh>>3)) & 3;
      *(ushort*)((char*)Vt + dh*64 + ((((skey>>3) ^ sw)&3)<<4) + (skey&7)*2) = vs[j];
    }
    __syncthreads();

    // S = Q K^T  (rows: q-local = 4g+r, cols: key = kb*16+lr)
    f32x4 s0acc = {0.f,0.f,0.f,0.f}, s1acc = {0.f,0.f,0.f,0.f};
    #pragma unroll
    for (int kc=0;kc<2;++kc) {
      bf16x8 kf0 = *(const bf16x8*)((const char*)Ks + lr*128      + (((kc*4+g) ^ (lr&7))<<4));
      s0acc = __builtin_amdgcn_mfma_f32_16x16x32_bf16(qf[kc], kf0, s0acc, 0,0,0);
      bf16x8 kf1 = *(const bf16x8*)((const char*)Ks + (16+lr)*128 + (((kc*4+g) ^ ((16+lr)&7))<<4));
      s1acc = __builtin_amdgcn_mfma_f32_16x16x32_bf16(qf[kc], kf1, s1acc, 0,0,0);
    }

    const float scale = 0.03125f;            // 1/sqrt(1024)
    #pragma unroll
    for (int r=0;r<4;++r) {
      const int qg = q0 + g*4 + r;
      float s0 = s0acc[r]*scale;
      float s1 = s1acc[r]*scale;
      if (kt*32 + lr      > qg) s0 = -1e30f; // causal (mask ≡ -inf pre-scale)
      if (kt*32 + 16 + lr > qg) s1 = -1e30f;
      float mx = fmaxf(s0, s1);
      #pragma unroll
      for (int d=1; d<16; d<<=1) mx = fmaxf(mx, __shfl_xor(mx, d));
      float mnew = fmaxf(mrow[r], mx);
      float al = __expf(mrow[r] - mnew);
      float p0 = __expf(s0 - mnew);
      float p1 = __expf(s1 - mnew);
      float rs = p0 + p1;
      #pragma unroll
      for (int d=1; d<16; d<<=1) rs += __shfl_xor(rs, d);
      lrow[r] = lrow[r]*al + rs;
      mrow[r] = mnew;
      #pragma unroll
      for (int nb=0;nb<4;++nb) oacc[nb][r] *= al;
      // P -> per-wave LDS scratch (bf16), re-layout for PV A-operand
      const int prow = g*4 + r;
      char* pb = (char*)&Ps[w][0] + prow*64 + (lr&7)*2;
      const int swp = (prow>>2)&3;
      *(__bf16*)(pb + (((((lr>>3)    ) ^ swp)&3)<<4)) = (__bf16)p0;
      *(__bf16*)(pb + (((((lr>>3) + 2) ^ swp)&3)<<4)) = (__bf16)p1;
    }

    // ensure same-wave Ps writes have landed before the re-layout read
    asm volatile("s_waitcnt lgkmcnt(0)" ::: "memory");

    // O += P V   (A = P rows q=lr, k=key; B = V[key][dh] from Vt)
    bf16x8 pa = *(const bf16x8*)((const char*)&Ps[w][0] + lr*64 + (((g ^ ((lr>>2)&3))&3)<<4));
    #pragma unroll
    for (int nb=0;nb<4;++nb) {
      int dh = nb*16 + lr;
      int sw = ((dh>>1) ^ (dh>>3)) & 3;
      bf16x8 vb = *(const bf16x8*)((const char*)Vt + dh*64 + (((g ^ sw)&3)<<4));
      oacc[nb] = __builtin_amdgcn_mfma_f32_16x16x32_bf16(pa, vb, oacc[nb], 0,0,0);
    }
  }

  #pragma unroll
  for (int nb=0;nb<4;++nb)
    #pragma unroll
    for (int r=0;r<4;++r) {
      float o = oacc[nb][r] / lrow[r];
      int row = q0 + g*4 + r;
      AO[(rb + row)*1024 + h*64 + nb*16 + lr] = (__bf16)o;
    }
}

extern "C" void kernel_launch(void* const* d_in, const int* in_sizes, int n_in,
                              void* d_out, int out_size, void* d_ws, size_t ws_size,
                              hipStream_t stream) {
  (void)in_sizes; (void)n_in; (void)out_size; (void)ws_size;
  const float* x  = (const float*)d_in[0];
  const float* Wq = (const float*)d_in[1];
  const float* Wk = (const float*)d_in[2];
  const float* Wv = (const float*)d_in[3];
  const float* Wo = (const float*)d_in[4];
  const float* bo = (const float*)d_in[5];
  float* out = (float*)d_out;
  char* ws = (char*)d_ws;

  // workspace layout (40 MiB total):
  __bf16* Xbf   = (__bf16*)(ws);                      // [0,8M)   x bf16; reused as AO
  __bf16* Wqkvt = (__bf16*)(ws + (size_t)(8<<20));    // [8M,14M) Wq|Wk|Wv transposed [3072][1024]
  __bf16* Wot   = (__bf16*)(ws + (size_t)(14<<20));   // [14M,16M) Wo transposed [1024][1024]
  __bf16* QKV   = (__bf16*)(ws + (size_t)(16<<20));   // [16M,40M) [4096][3072]
  __bf16* AO    = Xbf;

  k_convert<<<4096, 256, 0, stream>>>(x, Xbf);
  k_transw<<<dim3(16,16,4), 256, 0, stream>>>(Wq, Wk, Wv, Wo, Wqkvt, Wot);
  k_gemm_bt<0><<<dim3(24,32), 256, 0, stream>>>(Xbf, Wqkvt, (void*)QKV, nullptr, 1024, 3072);
  k_attn<<<dim3(32,32), 256, 0, stream>>>(QKV, AO);
  k_gemm_bt<1><<<dim3(8,32), 256, 0, stream>>>(AO, Wot, (void*)out, bo, 1024, 1024);
}

// Round 3
// 198.681 us; speedup vs baseline: 1.5913x; 1.5913x over previous
//
#include <hip/hip_runtime.h>

#define D_MODEL 1024
#define SEQ     2048
#define BATCH   2
#define NHEAD   16
#define HDIM    64

typedef __attribute__((ext_vector_type(4))) float  f32x4;
typedef __attribute__((ext_vector_type(8))) __bf16 bf16x8;
typedef __attribute__((ext_vector_type(4))) __bf16 bf16x4;
typedef __attribute__((ext_vector_type(2))) unsigned int u32x2;

__device__ __forceinline__ void gld_lds16(const void* g, void* l) {
  __builtin_amdgcn_global_load_lds(
      (const __attribute__((address_space(1))) void*)g,
      (__attribute__((address_space(3))) void*)l, 16, 0, 0);
}

// ---------------- convert x (fp32 -> bf16), vectorized ----------------
__global__ void k_convert(const float* __restrict__ in, __bf16* __restrict__ out) {
  int i = blockIdx.x * blockDim.x + threadIdx.x;   // one float4 per thread
  float4 v = ((const float4*)in)[i];
  bf16x4 o;
  o[0] = (__bf16)v.x; o[1] = (__bf16)v.y; o[2] = (__bf16)v.z; o[3] = (__bf16)v.w;
  ((bf16x4*)out)[i] = o;
}

// ------------- transpose + convert weights: W[k][n] -> Wt[n][k] bf16 -------------
// Wq is additionally scaled by 1/sqrt(D_MODEL) = 1/32 (exact in bf16).
__global__ void k_transw(const float* __restrict__ Wq, const float* __restrict__ Wk,
                         const float* __restrict__ Wv, const float* __restrict__ Wo,
                         __bf16* __restrict__ Wqkvt, __bf16* __restrict__ Wot) {
  __shared__ __bf16 T[64][72];
  const int z = blockIdx.z;
  const float* src = (z==0)?Wq:(z==1)?Wk:(z==2)?Wv:Wo;
  __bf16* dst = (z<3) ? (Wqkvt + (size_t)z*D_MODEL*D_MODEL) : Wot;
  const float scl = (z==0) ? 0.03125f : 1.0f;      // fold softmax scale into Wq
  const int k0 = blockIdx.x*64, n0 = blockIdx.y*64;
  const int t = threadIdx.x;
  const int kl = t>>4, nl4 = (t&15)*4;
  #pragma unroll
  for (int part = 0; part < 4; ++part) {
    const int k = part*16 + kl;
    float4 v = *(const float4*)(src + (size_t)(k0+k)*D_MODEL + n0 + nl4);
    T[nl4+0][k] = (__bf16)(v.x*scl);
    T[nl4+1][k] = (__bf16)(v.y*scl);
    T[nl4+2][k] = (__bf16)(v.z*scl);
    T[nl4+3][k] = (__bf16)(v.w*scl);
  }
  __syncthreads();
  const int nl = t>>3, kc = (t&7)*8;
  #pragma unroll
  for (int part = 0; part < 2; ++part) {
    int n = part*32 + nl;
    bf16x8 o = *(const bf16x8*)&T[n][kc];
    *(bf16x8*)(dst + (size_t)(n0+n)*D_MODEL + k0 + kc) = o;
  }
}

// ------------- bf16 MFMA GEMM, 128x128 tile, BK=32, Bt is [N][K] (m97 structure) -------------
template<int OUTF32>
__global__ __launch_bounds__(256)
void k_gemm_bt(const __bf16* __restrict__ A, const __bf16* __restrict__ Bt,
               void* __restrict__ Cv, const float* __restrict__ bias,
               const int K, const int N) {
  __shared__ __bf16 As[128*32];
  __shared__ __bf16 Bs[128*32];
  const int t = threadIdx.x;
  const int w = t>>6, l = t&63;
  const int lr = l&15, g = l>>4;
  const int m0 = blockIdx.y*128, n0 = blockIdx.x*128;
  const int wr = (w>>1)*64, wc = (w&1)*64;
  f32x4 acc[4][4] = {};

  const int srow = w*16 + (l>>2);
  const int sc8  = (l&3)*8;
  const __bf16* Ag = A  + (size_t)(m0 + srow)*K + sc8;
  const __bf16* Bg = Bt + (size_t)(n0 + srow)*K + sc8;
  char* Al = (char*)As + w*1024;
  char* Bl = (char*)Bs + w*1024;

  for (int k0 = 0; k0 < K; k0 += 32) {
    __syncthreads();
    gld_lds16(Ag + k0,                 Al);
    gld_lds16(Ag + (size_t)64*K + k0,  Al + 4096);
    gld_lds16(Bg + k0,                 Bl);
    gld_lds16(Bg + (size_t)64*K + k0,  Bl + 4096);
    __syncthreads();
    bf16x8 af[4], bf[4];
    #pragma unroll
    for (int mi=0;mi<4;++mi)
      af[mi] = *(const bf16x8*)((const char*)As + (wr + mi*16 + lr)*64 + (g<<4));
    #pragma unroll
    for (int ni=0;ni<4;++ni)
      bf[ni] = *(const bf16x8*)((const char*)Bs + (wc + ni*16 + lr)*64 + (g<<4));
    #pragma unroll
    for (int mi=0;mi<4;++mi)
      #pragma unroll
      for (int ni=0;ni<4;++ni)
        acc[mi][ni] = __builtin_amdgcn_mfma_f32_16x16x32_bf16(af[mi], bf[ni], acc[mi][ni], 0, 0, 0);
  }

  if (OUTF32) {
    float* C = (float*)Cv;
    #pragma unroll
    for (int ni=0;ni<4;++ni) {
      const int col = n0 + wc + ni*16 + lr;
      const float bv = bias[col];
      #pragma unroll
      for (int mi=0;mi<4;++mi)
        #pragma unroll
        for (int r=0;r<4;++r) {
          const int row = m0 + wr + mi*16 + g*4 + r;
          C[(size_t)row*N + col] = acc[mi][ni][r] + bv;
        }
    }
  } else {
    __bf16* C = (__bf16*)Cv;
    #pragma unroll
    for (int ni=0;ni<4;++ni) {
      const int col = n0 + wc + ni*16 + lr;
      #pragma unroll
      for (int mi=0;mi<4;++mi)
        #pragma unroll
        for (int r=0;r<4;++r) {
          const int row = m0 + wr + mi*16 + g*4 + r;
          C[(size_t)row*N + col] = (__bf16)acc[mi][ni][r];
        }
    }
  }
}

// ------------- causal flash attention, swapped-QK^T structure -------------
// QKV: [4096][3072] bf16 (Q|K|V, per-head 64). Q pre-scaled by 1/32 via Wq.
// Per block: TWO 64-row q-tiles (qb=bx and 31-bx) -> uniform 33 iters/block.
// Per warp: 16 q-rows. KVBLK=64, double-buffered LDS, reg-prefetch (T14).
// Swapped QK^T: sa slot (g,r) of acc kb = score[q=q0+lane&15][key=kt*64+kb*16+4g+r].
// PV: pa packed lane-locally; V read via ds_read_b64_tr_b16 from subtiled LDS.
__global__ __launch_bounds__(256)
void k_attn(const __bf16* __restrict__ QKV, __bf16* __restrict__ AO) {
  __shared__ __bf16 Ks[2][64*64];   // [key][dh] rows 128B, chunk ^= (key&7)
  __shared__ __bf16 Vs[2][64*64];   // subtiled [kb][nb][16][16] row-major, 512B each
  const int t = threadIdx.x;
  const int w = t>>6, l = t&63;
  const int lr = l&15, g = l>>4;
  const int bh = blockIdx.y, b = bh>>4, h = bh&15;
  const size_t rb = (size_t)b*SEQ;

  // staging: thread -> (key row skey / skey+32, dh chunk sc*8)
  const int skey = t>>3, sc = t&7;
  const __bf16* Kg = QKV + rb*3072 + 1024 + h*64 + sc*8;
  const __bf16* Vg = Kg + 1024;
  const int ksw = skey*128 + ((sc ^ (skey&7))<<4);                       // K write byte off
  const int vsw = ((skey>>4)*4 + (sc>>1))*512 + (skey&15)*32 + (sc&1)*16; // V write byte off

  for (int half = 0; half < 2; ++half) {
    const int qb = (half==0) ? (int)blockIdx.x : 31 - (int)blockIdx.x;
    const int nt = qb + 1;
    const int q0 = qb*64 + w*16;

    // Q fragments (B-operand: col q = q0+lr, k-slice dh = kc*32+g*8)
    bf16x8 qf[2];
    #pragma unroll
    for (int kc=0;kc<2;++kc)
      qf[kc] = *(const bf16x8*)(QKV + (rb + q0 + lr)*3072 + h*64 + kc*32 + g*8);

    f32x4 oacc[4] = {};
    float mrun = -1e30f, lrun = 0.f;

    // prologue: tile 0 -> regs -> LDS buf0; then prefetch tile 1 -> regs
    uint4 kR0 = *(const uint4*)(Kg + (size_t)skey*3072);
    uint4 kR1 = *(const uint4*)(Kg + (size_t)(skey+32)*3072);
    uint4 vR0 = *(const uint4*)(Vg + (size_t)skey*3072);
    uint4 vR1 = *(const uint4*)(Vg + (size_t)(skey+32)*3072);
    __syncthreads();                       // prev-half readers done with buffers
    {
      char* K0 = (char*)&Ks[0][0]; char* V0 = (char*)&Vs[0][0];
      *(uint4*)(K0 + ksw) = kR0;  *(uint4*)(K0 + ksw + 4096) = kR1;
      *(uint4*)(V0 + vsw) = vR0;  *(uint4*)(V0 + vsw + 4096) = vR1;
    }
    if (nt > 1) {
      kR0 = *(const uint4*)(Kg + (size_t)(64+skey)*3072);
      kR1 = *(const uint4*)(Kg + (size_t)(64+skey+32)*3072);
      vR0 = *(const uint4*)(Vg + (size_t)(64+skey)*3072);
      vR1 = *(const uint4*)(Vg + (size_t)(64+skey+32)*3072);
    }

    int cur = 0;
    for (int kt = 0; kt < nt; ++kt) {
      __syncthreads();                     // buf[cur] fully written; prev reads done
      if (kt+1 < nt) {                     // stage next tile into other buffer
        char* Kn = (char*)&Ks[cur^1][0]; char* Vn = (char*)&Vs[cur^1][0];
        *(uint4*)(Kn + ksw) = kR0;  *(uint4*)(Kn + ksw + 4096) = kR1;
        *(uint4*)(Vn + vsw) = vR0;  *(uint4*)(Vn + vsw + 4096) = vR1;
        if (kt+2 < nt) {                   // issue loads for tile kt+2 (hide under compute)
          const size_t base = (size_t)(kt+2)*64;
          kR0 = *(const uint4*)(Kg + (base+skey)*3072);
          kR1 = *(const uint4*)(Kg + (base+skey+32)*3072);
          vR0 = *(const uint4*)(Vg + (base+skey)*3072);
          vR1 = *(const uint4*)(Vg + (base+skey+32)*3072);
        }
      }

      // ---- QK^T (swapped: A=K rows, B=Q cols) ----
      const char* Kb = (const char*)&Ks[cur][0];
      f32x4 sa[4] = {};
      #pragma unroll
      for (int kc=0;kc<2;++kc)
        #pragma unroll
        for (int kb=0;kb<4;++kb) {
          bf16x8 kfv = *(const bf16x8*)(Kb + (kb*16+lr)*128 + (((kc*4+g) ^ (lr&7))<<4));
          sa[kb] = __builtin_amdgcn_mfma_f32_16x16x32_bf16(kfv, qf[kc], sa[kb], 0,0,0);
        }

      if (kt == nt-1) {                    // diagonal tile: causal mask
        const int qg = q0 + lr;
        #pragma unroll
        for (int kb=0;kb<4;++kb)
          #pragma unroll
          for (int r=0;r<4;++r)
            if (kt*64 + kb*16 + 4*g + r > qg) sa[kb][r] = -1e30f;
      }

      // ---- online softmax (lane-local row q=q0+lr; reduce over 4 g-lanes) ----
      float mx = sa[0][0];
      #pragma unroll
      for (int kb=0;kb<4;++kb)
        #pragma unroll
        for (int r=0;r<4;++r) mx = fmaxf(mx, sa[kb][r]);
      mx = fmaxf(mx, __shfl_xor(mx, 16));
      mx = fmaxf(mx, __shfl_xor(mx, 32));
      const float mnew = fmaxf(mrun, mx);
      const float al = __expf(mrun - mnew);
      mrun = mnew;
      float ls = 0.f;
      #pragma unroll
      for (int kb=0;kb<4;++kb)
        #pragma unroll
        for (int r=0;r<4;++r) { float p = __expf(sa[kb][r]-mnew); sa[kb][r] = p; ls += p; }
      ls += __shfl_xor(ls, 16);
      ls += __shfl_xor(ls, 32);
      lrun = lrun*al + ls;
      float alq[4];
      #pragma unroll
      for (int r=0;r<4;++r) alq[r] = __shfl(al, g*4+r);   // al for q-row 4g+r (oacc layout)
      #pragma unroll
      for (int nb=0;nb<4;++nb)
        #pragma unroll
        for (int r=0;r<4;++r) oacc[nb][r] *= alq[r];

      // ---- PV: pa lane-local pack; V via hw transpose read ----
      const __attribute__((address_space(3))) char* trp =
          (const __attribute__((address_space(3))) char*)((const char*)&Vs[cur][0]) + l*8;
      #pragma unroll
      for (int kc=0;kc<2;++kc) {
        bf16x8 pa;
        #pragma unroll
        for (int j=0;j<4;++j) { pa[j] = (__bf16)sa[2*kc][j]; pa[4+j] = (__bf16)sa[2*kc+1][j]; }
        u32x2 t0[4], t1[4];
        #pragma unroll
        for (int nb=0;nb<4;++nb) {
          asm volatile("ds_read_b64_tr_b16 %0, %1 offset:%2"
                       : "=v"(t0[nb]) : "v"(trp), "i"(((2*kc)*4+nb)*512) : "memory");
          asm volatile("ds_read_b64_tr_b16 %0, %1 offset:%2"
                       : "=v"(t1[nb]) : "v"(trp), "i"(((2*kc+1)*4+nb)*512) : "memory");
        }
        asm volatile("s_waitcnt lgkmcnt(0)" ::: "memory");
        __builtin_amdgcn_sched_barrier(0);   // rule 18: don't hoist MFMA above the wait
        #pragma unroll
        for (int nb=0;nb<4;++nb) {
          union { u32x2 h[2]; bf16x8 v; } U;
          U.h[0] = t0[nb]; U.h[1] = t1[nb];
          oacc[nb] = __builtin_amdgcn_mfma_f32_16x16x32_bf16(pa, U.v, oacc[nb], 0,0,0);
        }
      }
      cur ^= 1;
    }

    // ---- epilogue: divide by l, write AO ----
    const float rinv = 1.0f / lrun;
    float rq[4];
    #pragma unroll
    for (int r=0;r<4;++r) rq[r] = __shfl(rinv, g*4+r);
    #pragma unroll
    for (int nb=0;nb<4;++nb)
      #pragma unroll
      for (int r=0;r<4;++r)
        AO[(rb + q0 + g*4 + r)*1024 + h*64 + nb*16 + lr] = (__bf16)(oacc[nb][r] * rq[r]);
  }
}

extern "C" void kernel_launch(void* const* d_in, const int* in_sizes, int n_in,
                              void* d_out, int out_size, void* d_ws, size_t ws_size,
                              hipStream_t stream) {
  (void)in_sizes; (void)n_in; (void)out_size; (void)ws_size;
  const float* x  = (const float*)d_in[0];
  const float* Wq = (const float*)d_in[1];
  const float* Wk = (const float*)d_in[2];
  const float* Wv = (const float*)d_in[3];
  const float* Wo = (const float*)d_in[4];
  const float* bo = (const float*)d_in[5];
  float* out = (float*)d_out;
  char* ws = (char*)d_ws;

  __bf16* Xbf   = (__bf16*)(ws);                      // [0,8M)   x bf16; reused as AO
  __bf16* Wqkvt = (__bf16*)(ws + (size_t)(8<<20));    // [8M,14M) Wq|Wk|Wv ^T [3072][1024]
  __bf16* Wot   = (__bf16*)(ws + (size_t)(14<<20));   // [14M,16M) Wo ^T [1024][1024]
  __bf16* QKV   = (__bf16*)(ws + (size_t)(16<<20));   // [16M,40M) [4096][3072]
  __bf16* AO    = Xbf;

  k_convert<<<4096, 256, 0, stream>>>(x, Xbf);
  k_transw<<<dim3(16,16,4), 256, 0, stream>>>(Wq, Wk, Wv, Wo, Wqkvt, Wot);
  k_gemm_bt<0><<<dim3(24,32), 256, 0, stream>>>(Xbf, Wqkvt, (void*)QKV, nullptr, 1024, 3072);
  k_attn<<<dim3(16,32), 256, 0, stream>>>(QKV, AO);
  k_gemm_bt<1><<<dim3(8,32), 256, 0, stream>>>(AO, Wot, (void*)out, bo, 1024, 1024);
}